// Round 2
// baseline (619.936 us; speedup 1.0000x reference)
//
#include <hip/hip_runtime.h>
#include <hip/hip_bf16.h>

#define EPS 1e-8f

constexpr int B_   = 8192;
constexpr int IN_  = 2048;
constexpr int OUT_ = 2048;
constexpr int G_   = 5;
constexpr int KA_  = IN_ * 6;   // augmented K: [x, basis0..4] per input feature

typedef __bf16 bf16x8 __attribute__((ext_vector_type(8)));
typedef float  f32x4  __attribute__((ext_vector_type(4)));

__device__ __forceinline__ ushort f2bf(float f) {
    union { float f; uint u; } v; v.f = f;
    uint u = v.u;
    uint r = u + 0x7fffu + ((u >> 16) & 1u);   // RNE
    return (ushort)(r >> 16);
}

__device__ __forceinline__ void gload16(const void* g, void* l) {
    __builtin_amdgcn_global_load_lds(
        (const __attribute__((address_space(1))) void*)g,
        (__attribute__((address_space(3))) void*)l,
        16, 0, 0);
}

// ---------------------------------------------------------------------------
// Stage A: A_aug[b, i*6+c] bf16.  Per-i reciprocals hoisted across 16 b-rows.
// grid: (B_/16, IN_/256), block 256 (thread <-> i)
// ---------------------------------------------------------------------------
__global__ __launch_bounds__(256) void stage_a(const float* __restrict__ x,
                                               const float* __restrict__ grid,
                                               ushort* __restrict__ A) {
    __shared__ __attribute__((aligned(16))) ushort pack[1536];
    const int tid = threadIdx.x;
    const int b0  = blockIdx.x * 16;
    const int i0  = blockIdx.y * 256;
    const int i   = i0 + tid;

    float g[5];
#pragma unroll
    for (int j = 0; j < 5; ++j) g[j] = grid[i * 5 + j];

    // 18 reciprocals (b-independent): r1/r2 per (order, j)
    float r1[9], r2[9];
    {
        int t = 0;
#pragma unroll
        for (int o = 1; o <= 3; ++o) {
#pragma unroll
            for (int j = 0; j < 5 - o; ++j) {
                int i2 = min(j + o, 4);
                int i3 = min(j + o + 1, 4);
                r1[t] = 1.0f / (g[i2] - g[j] + EPS);
                r2[t] = 1.0f / (g[i3] - g[j + 1] + EPS);
                ++t;
            }
        }
    }

    for (int r = 0; r < 16; ++r) {
        const int b = b0 + r;
        float xv = x[(size_t)b * IN_ + i];
        float diff[5], bas[5];
#pragma unroll
        for (int j = 0; j < 5; ++j) {
            diff[j] = xv - g[j];
            bas[j]  = (diff[j] >= 0.0f && diff[j] < 1.0f) ? 1.0f : 0.0f;
        }
        int t = 0;
#pragma unroll
        for (int o = 1; o <= 3; ++o) {
            float nb[4];
#pragma unroll
            for (int j = 0; j < 5 - o; ++j) {
                int i3 = min(j + o + 1, 4);
                float t1 = (diff[j] - g[j]) * r1[t] * bas[j];
                float t2 = (g[i3] - diff[j]) * r2[t] * bas[j + 1];
                nb[j] = t1 + t2;
                ++t;
            }
#pragma unroll
            for (int j = 0; j < 5 - o; ++j) bas[j] = nb[j];
        }

        pack[tid * 6 + 0] = f2bf(xv);
#pragma unroll
        for (int j = 0; j < 5; ++j) pack[tid * 6 + 1 + j] = f2bf(bas[j]);
        __syncthreads();
        {
            const uint* ps = (const uint*)pack;
            uint* pd = (uint*)(A + (size_t)b * KA_ + (size_t)i0 * 6);
#pragma unroll
            for (int j = 0; j < 3; ++j) pd[tid + j * 256] = ps[tid + j * 256];
        }
        __syncthreads();
    }
}

// ---------------------------------------------------------------------------
// Stage W: W_aug[o, i*6+c] bf16 (c0 = base_weight, c1..5 = spline_weight)
// grid: (OUT_, IN_/256), block 256 (thread <-> i)
// ---------------------------------------------------------------------------
__global__ __launch_bounds__(256) void stage_w(const float* __restrict__ bw,
                                               const float* __restrict__ sw,
                                               ushort* __restrict__ W) {
    __shared__ __attribute__((aligned(16))) float  ssh[1280];
    __shared__ __attribute__((aligned(16))) ushort wsh[1536];
    const int tid = threadIdx.x;
    const int o   = blockIdx.x;
    const int i0  = blockIdx.y * 256;

    const float* sp = sw + ((size_t)o * IN_ + i0) * 5;
    for (int j = tid; j < 1280; j += 256) ssh[j] = sp[j];
    float bwv = bw[(size_t)o * IN_ + i0 + tid];
    __syncthreads();

    wsh[tid * 6] = f2bf(bwv);
#pragma unroll
    for (int j = 0; j < 5; ++j) wsh[tid * 6 + 1 + j] = f2bf(ssh[tid * 5 + j]);
    __syncthreads();

    const uint* ps = (const uint*)wsh;
    uint* pd = (uint*)(W + (size_t)o * KA_ + (size_t)i0 * 6);
#pragma unroll
    for (int j = 0; j < 3; ++j) pd[tid + j * 256] = ps[tid + j * 256];
}

// ---------------------------------------------------------------------------
// GEMM: C[b,o] = A_aug[b,:] . W_aug[o,:] + bias[o]
// 128x128 tile, BK=64, 4 waves (each 64x64), 16x16x32 bf16 MFMA,
// global_load_lds width-16 with XOR-swizzled source (slot ^= row&7).
// grid: (OUT_/128, B_/128), block 256
// ---------------------------------------------------------------------------
__global__ __launch_bounds__(256) void gemm_kan(const ushort* __restrict__ A,
                                                const ushort* __restrict__ W,
                                                const float* __restrict__ bias,
                                                float* __restrict__ out) {
    __shared__ __attribute__((aligned(16))) ushort As[128 * 64];
    __shared__ __attribute__((aligned(16))) ushort Ws[128 * 64];

    const int tid  = threadIdx.x;
    const int lane = tid & 63;
    const int wave = tid >> 6;
    const int wr   = wave >> 1;   // wave row (0..1)
    const int wc   = wave & 1;    // wave col (0..1)
    const int bn   = blockIdx.x;
    const int bm   = blockIdx.y;

    f32x4 acc[4][4];
#pragma unroll
    for (int m = 0; m < 4; ++m)
#pragma unroll
        for (int n = 0; n < 4; ++n)
            acc[m][n] = (f32x4){0.f, 0.f, 0.f, 0.f};

    // staging offsets: chunk c = wave + 4j writes LDS bytes [c*1024, c*1024+1024)
    // linear LDS <-> swizzled global source: ls = (lane&7) ^ (lane>>3)
    uint goff[4], loff[4];
    {
        const uint ls = (uint)((lane & 7) ^ (lane >> 3)) * 8u;  // element offset in row
#pragma unroll
        for (int j = 0; j < 4; ++j) {
            uint c   = (uint)wave + 4u * j;
            uint row = c * 8u + (uint)(lane >> 3);
            goff[j]  = row * (uint)KA_ + ls;
            loff[j]  = c * 1024u;
        }
    }

    const ushort* Ab = A + (size_t)bm * 128 * KA_;
    const ushort* Wb = W + (size_t)bn * 128 * KA_;

    for (int kt = 0; kt < KA_ / 64; ++kt) {
#pragma unroll
        for (int j = 0; j < 4; ++j) {
            gload16(Ab + goff[j], (char*)As + loff[j]);
            gload16(Wb + goff[j], (char*)Ws + loff[j]);
        }
        __syncthreads();

#pragma unroll
        for (int ks = 0; ks < 2; ++ks) {
            bf16x8 af[4], wf[4];
#pragma unroll
            for (int m = 0; m < 4; ++m) {
                uint row  = (uint)(wr * 64 + m * 16 + (lane & 15));
                uint slot = ((uint)(ks * 4 + (lane >> 4))) ^ (row & 7u);
                af[m] = *(const bf16x8*)((const char*)As + row * 128u + slot * 16u);
            }
#pragma unroll
            for (int n = 0; n < 4; ++n) {
                uint row  = (uint)(wc * 64 + n * 16 + (lane & 15));
                uint slot = ((uint)(ks * 4 + (lane >> 4))) ^ (row & 7u);
                wf[n] = *(const bf16x8*)((const char*)Ws + row * 128u + slot * 16u);
            }
#pragma unroll
            for (int m = 0; m < 4; ++m)
#pragma unroll
                for (int n = 0; n < 4; ++n)
                    acc[m][n] = __builtin_amdgcn_mfma_f32_16x16x32_bf16(
                        af[m], wf[n], acc[m][n], 0, 0, 0);
        }
        __syncthreads();
        Ab += 64;
        Wb += 64;
    }

    // epilogue: C/D layout col=lane&15, row=(lane>>4)*4+j  (guide-verified)
    const int orow0 = bm * 128 + wr * 64;
    const int ocol0 = bn * 128 + wc * 64;
#pragma unroll
    for (int n = 0; n < 4; ++n) {
        int c = ocol0 + n * 16 + (lane & 15);
        float bv = bias[c];
#pragma unroll
        for (int m = 0; m < 4; ++m) {
            int r0 = orow0 + m * 16 + ((lane >> 4) << 2);
#pragma unroll
            for (int j = 0; j < 4; ++j)
                out[(size_t)(r0 + j) * OUT_ + c] = acc[m][n][j] + bv;
        }
    }
}

// ---------------------------------------------------------------------------
// Fallback (no workspace): correct f32 path, 16 b-rows x 256 o-cols per block
// ---------------------------------------------------------------------------
__global__ __launch_bounds__(256) void kan_fallback(const float* __restrict__ x,
                                                    const float* __restrict__ bw,
                                                    const float* __restrict__ bb,
                                                    const float* __restrict__ sw,
                                                    const float* __restrict__ grid,
                                                    float* __restrict__ out) {
    __shared__ float ash[16 * 384];
    const int tid = threadIdx.x;
    const int o   = blockIdx.x * 256 + tid;
    const int b0  = blockIdx.y * 16;
    float acc[16];
#pragma unroll
    for (int r = 0; r < 16; ++r) acc[r] = 0.0f;

    for (int ic = 0; ic < IN_; ic += 64) {
        __syncthreads();
        for (int p = tid; p < 1024; p += 256) {
            int r = p >> 6, ii = p & 63;
            int i = ic + ii;
            float xv = x[(size_t)(b0 + r) * IN_ + i];
            float g[5];
#pragma unroll
            for (int j = 0; j < 5; ++j) g[j] = grid[i * 5 + j];
            float diff[5], bas[5];
#pragma unroll
            for (int j = 0; j < 5; ++j) {
                diff[j] = xv - g[j];
                bas[j]  = (diff[j] >= 0.0f && diff[j] < 1.0f) ? 1.0f : 0.0f;
            }
#pragma unroll
            for (int oo = 1; oo <= 3; ++oo) {
                float nb[4];
#pragma unroll
                for (int j = 0; j < 5 - oo; ++j) {
                    int i2 = min(j + oo, 4);
                    int i3 = min(j + oo + 1, 4);
                    nb[j] = (diff[j] - g[j]) / (g[i2] - g[j] + EPS) * bas[j]
                          + (g[i3] - diff[j]) / (g[i3] - g[j + 1] + EPS) * bas[j + 1];
                }
#pragma unroll
                for (int j = 0; j < 5 - oo; ++j) bas[j] = nb[j];
            }
            float* ap = &ash[r * 384 + ii * 6];
            ap[0] = xv;
#pragma unroll
            for (int j = 0; j < 5; ++j) ap[1 + j] = bas[j];
        }
        __syncthreads();
        for (int ii = 0; ii < 64; ++ii) {
            int i = ic + ii;
            float w0 = bw[(size_t)o * IN_ + i];
            const float* swp = sw + ((size_t)o * IN_ + i) * 5;
            float w1 = swp[0], w2 = swp[1], w3 = swp[2], w4 = swp[3], w5 = swp[4];
#pragma unroll
            for (int r = 0; r < 16; ++r) {
                const float* a = &ash[r * 384 + ii * 6];
                acc[r] += a[0] * w0 + a[1] * w1 + a[2] * w2
                        + a[3] * w3 + a[4] * w4 + a[5] * w5;
            }
        }
    }
    float bv = bb[o];
#pragma unroll
    for (int r = 0; r < 16; ++r)
        out[(size_t)(b0 + r) * OUT_ + o] = acc[r] + bv;
}

extern "C" void kernel_launch(void* const* d_in, const int* in_sizes, int n_in,
                              void* d_out, int out_size, void* d_ws, size_t ws_size,
                              hipStream_t stream) {
    (void)in_sizes; (void)n_in; (void)out_size;
    const float* x    = (const float*)d_in[0];
    const float* bw   = (const float*)d_in[1];
    const float* bb   = (const float*)d_in[2];
    const float* sw   = (const float*)d_in[3];
    const float* grid = (const float*)d_in[4];
    float* out = (float*)d_out;

    const size_t needA = (size_t)B_ * KA_ * sizeof(ushort);
    const size_t needW = (size_t)OUT_ * KA_ * sizeof(ushort);

    if (ws_size >= needA + needW) {
        ushort* A = (ushort*)d_ws;
        ushort* W = A + (size_t)B_ * KA_;
        stage_a<<<dim3(B_ / 16, IN_ / 256), 256, 0, stream>>>(x, grid, A);
        stage_w<<<dim3(OUT_, IN_ / 256), 256, 0, stream>>>(bw, sw, W);
        gemm_kan<<<dim3(OUT_ / 128, B_ / 128), 256, 0, stream>>>(A, W, bb, out);
    } else {
        kan_fallback<<<dim3(OUT_ / 256, B_ / 16), 256, 0, stream>>>(x, bw, bb, sw, grid, out);
    }
}

// Round 3
// 446.416 us; speedup vs baseline: 1.3887x; 1.3887x over previous
//
#include <hip/hip_runtime.h>
#include <hip/hip_bf16.h>

#define EPS 1e-8f

constexpr int B_   = 8192;
constexpr int IN_  = 2048;
constexpr int OUT_ = 2048;
constexpr int KA_  = IN_ * 6;   // augmented K: [x, basis0..4] per input feature
constexpr int NT_  = KA_ / 64;  // 192 K-tiles of BK=64

typedef __bf16 bf16x8 __attribute__((ext_vector_type(8)));
typedef float  f32x4  __attribute__((ext_vector_type(4)));

__device__ __forceinline__ ushort f2bf(float f) {
    union { float f; uint u; } v; v.f = f;
    uint u = v.u;
    uint r = u + 0x7fffu + ((u >> 16) & 1u);   // RNE
    return (ushort)(r >> 16);
}

__device__ __forceinline__ void gload16(const void* g, void* l) {
    __builtin_amdgcn_global_load_lds(
        (const __attribute__((address_space(1))) void*)g,
        (__attribute__((address_space(3))) void*)l,
        16, 0, 0);
}

// ---------------------------------------------------------------------------
// Stage A: A_aug[b, i*6+c] bf16.  (unchanged, passed R2)
// ---------------------------------------------------------------------------
__global__ __launch_bounds__(256) void stage_a(const float* __restrict__ x,
                                               const float* __restrict__ grid,
                                               ushort* __restrict__ A) {
    __shared__ __attribute__((aligned(16))) ushort pack[1536];
    const int tid = threadIdx.x;
    const int b0  = blockIdx.x * 16;
    const int i0  = blockIdx.y * 256;
    const int i   = i0 + tid;

    float g[5];
#pragma unroll
    for (int j = 0; j < 5; ++j) g[j] = grid[i * 5 + j];

    float r1[9], r2[9];
    {
        int t = 0;
#pragma unroll
        for (int o = 1; o <= 3; ++o) {
#pragma unroll
            for (int j = 0; j < 5 - o; ++j) {
                int i2 = min(j + o, 4);
                int i3 = min(j + o + 1, 4);
                r1[t] = 1.0f / (g[i2] - g[j] + EPS);
                r2[t] = 1.0f / (g[i3] - g[j + 1] + EPS);
                ++t;
            }
        }
    }

    for (int r = 0; r < 16; ++r) {
        const int b = b0 + r;
        float xv = x[(size_t)b * IN_ + i];
        float diff[5], bas[5];
#pragma unroll
        for (int j = 0; j < 5; ++j) {
            diff[j] = xv - g[j];
            bas[j]  = (diff[j] >= 0.0f && diff[j] < 1.0f) ? 1.0f : 0.0f;
        }
        int t = 0;
#pragma unroll
        for (int o = 1; o <= 3; ++o) {
            float nb[4];
#pragma unroll
            for (int j = 0; j < 5 - o; ++j) {
                int i3 = min(j + o + 1, 4);
                float t1 = (diff[j] - g[j]) * r1[t] * bas[j];
                float t2 = (g[i3] - diff[j]) * r2[t] * bas[j + 1];
                nb[j] = t1 + t2;
                ++t;
            }
#pragma unroll
            for (int j = 0; j < 5 - o; ++j) bas[j] = nb[j];
        }

        pack[tid * 6 + 0] = f2bf(xv);
#pragma unroll
        for (int j = 0; j < 5; ++j) pack[tid * 6 + 1 + j] = f2bf(bas[j]);
        __syncthreads();
        {
            const uint* ps = (const uint*)pack;
            uint* pd = (uint*)(A + (size_t)b * KA_ + (size_t)i0 * 6);
#pragma unroll
            for (int j = 0; j < 3; ++j) pd[tid + j * 256] = ps[tid + j * 256];
        }
        __syncthreads();
    }
}

// ---------------------------------------------------------------------------
// Stage W: W_aug[o, i*6+c] bf16.  (unchanged, passed R2)
// ---------------------------------------------------------------------------
__global__ __launch_bounds__(256) void stage_w(const float* __restrict__ bw,
                                               const float* __restrict__ sw,
                                               ushort* __restrict__ W) {
    __shared__ __attribute__((aligned(16))) float  ssh[1280];
    __shared__ __attribute__((aligned(16))) ushort wsh[1536];
    const int tid = threadIdx.x;
    const int o   = blockIdx.x;
    const int i0  = blockIdx.y * 256;

    const float* sp = sw + ((size_t)o * IN_ + i0) * 5;
    for (int j = tid; j < 1280; j += 256) ssh[j] = sp[j];
    float bwv = bw[(size_t)o * IN_ + i0 + tid];
    __syncthreads();

    wsh[tid * 6] = f2bf(bwv);
#pragma unroll
    for (int j = 0; j < 5; ++j) wsh[tid * 6 + 1 + j] = f2bf(ssh[tid * 5 + j]);
    __syncthreads();

    const uint* ps = (const uint*)wsh;
    uint* pd = (uint*)(W + (size_t)o * KA_ + (size_t)i0 * 6);
#pragma unroll
    for (int j = 0; j < 3; ++j) pd[tid + j * 256] = ps[tid + j * 256];
}

// ---------------------------------------------------------------------------
// GEMM, 256x256 8-phase template (T1+T2+T3+T4+T5):
//   BM=BN=256, BK=64, 512 thr (8 waves, 2Mx4N), per-wave 128x64 out.
//   LDS 128 KiB: 2 slots x (A[256][64] + W[256][64]) bf16, st_16x32 swizzle
//   (phys = linear ^ ((bit9(linear))<<5)), linear gload_lds dest +
//   inverse-swizzled global source + swizzled ds_read (both-sides rule).
//   8 phases / 2 K-tiles per iter; counted vmcnt(4) at phases 4 & 8 only.
//   Stage ledger (region staged >=1 phase after its last ds_read):
//     P1:s1.Alo(t1)  P2:s1.Ahi(t1)  P3:s0.Wlo(t0+2)  P4:s0.Whi(t0+2)+vmcnt4
//     P5:s0.Alo(t0+2) P6:s0.Ahi(t0+2) P7:s1.Wlo(t1+2) P8:s1.Whi(t1+2)+vmcnt4
// grid: 256 blocks (1/CU), XCD-swizzled (256%8==0 -> bijective)
// ---------------------------------------------------------------------------
__global__ __launch_bounds__(512, 2) void gemm_kan8(const ushort* __restrict__ A,
                                                    const ushort* __restrict__ W,
                                                    const float* __restrict__ bias,
                                                    float* __restrict__ out) {
    __shared__ __attribute__((aligned(16))) char lds[2][2][32768];

    const int tid  = threadIdx.x;
    const int lane = tid & 63;
    const int wave = tid >> 6;
    const int wr   = wave >> 2;   // 0..1
    const int wc   = wave & 3;    // 0..3

    uint bid = blockIdx.x;
    uint swz = (bid & 7u) * 32u + (bid >> 3);   // XCD-contiguous chunks
    const int bm = (int)(swz >> 3);             // 0..31
    const int bn = (int)(swz & 7u);             // 0..7

    const uint lhi16 = ((uint)lane >> 4) * 16u;
    const uint swx   = ((uint)lane & 4u) << 3;  // row&4 -> byte-bit5 XOR
    uint aro[8], wro[4];
#pragma unroll
    for (int m = 0; m < 8; ++m) aro[m] = (uint)(wr * 128 + m * 16 + (lane & 15)) * 128u;
#pragma unroll
    for (int n = 0; n < 4; ++n) wro[n] = (uint)(wc * 64 + n * 16 + (lane & 15)) * 128u;

    // staging: chunk c=wave (q0) / 8+wave (q1); lane -> row c*8+(lane>>3),
    // source col pre-swizzled: elem = ((lane&7)^((lane>>5)<<1))*8
    const uint srow0 = (uint)wave * 8u + ((uint)lane >> 3);
    const uint srow1 = srow0 + 64u;
    const uint gcol  = (((uint)lane & 7u) ^ (((uint)lane >> 5) << 1)) * 8u;
    const ushort* pA0 = A + (size_t)bm * 256 * KA_ + (size_t)srow0 * KA_ + gcol;
    const ushort* pA1 = A + (size_t)bm * 256 * KA_ + (size_t)srow1 * KA_ + gcol;
    const ushort* pW0 = W + (size_t)bn * 256 * KA_ + (size_t)srow0 * KA_ + gcol;
    const ushort* pW1 = W + (size_t)bn * 256 * KA_ + (size_t)srow1 * KA_ + gcol;
    const uint c0off = (uint)wave * 1024u;
    const uint c1off = c0off + 8192u;

    f32x4 acc[8][4];
#pragma unroll
    for (int m = 0; m < 8; ++m)
#pragma unroll
        for (int n = 0; n < 4; ++n)
            acc[m][n] = (f32x4){0.f, 0.f, 0.f, 0.f};

#define DSR(base, ro, kh) (*(const bf16x8*)((base) + (ro) + (((kh) * 64u + lhi16) ^ swx)))

#define STAGE(s, mat, h, kk, PT0, PT1) do {                                   \
        uint kc_ = (uint)((kk) < NT_ ? (kk) : 0);                             \
        size_t go_ = (size_t)(h) * 128 * KA_ + (size_t)kc_ * 64;              \
        gload16(PT0 + go_, &lds[s][mat][(h) * 16384 + c0off]);                \
        gload16(PT1 + go_, &lds[s][mat][(h) * 16384 + c1off]);                \
    } while (0)

#define RDA(dst, base, mb) do {                                               \
        _Pragma("unroll") for (int m_ = 0; m_ < 4; ++m_) {                    \
            dst[m_][0] = DSR(base, aro[(mb) + m_], 0);                        \
            dst[m_][1] = DSR(base, aro[(mb) + m_], 1); } } while (0)

#define RDB(dst, base, nb) do {                                               \
        _Pragma("unroll") for (int n_ = 0; n_ < 2; ++n_) {                    \
            dst[n_][0] = DSR(base, wro[(nb) + n_], 0);                        \
            dst[n_][1] = DSR(base, wro[(nb) + n_], 1); } } while (0)

#define MIDBAR() do { __builtin_amdgcn_s_barrier();                           \
        asm volatile("s_waitcnt lgkmcnt(0)" ::: "memory");                    \
        __builtin_amdgcn_sched_barrier(0); } while (0)

#define MFMAQ(AF, BF, MB, NB) do {                                            \
        __builtin_amdgcn_s_setprio(1);                                        \
        _Pragma("unroll") for (int m_ = 0; m_ < 4; ++m_)                      \
        _Pragma("unroll") for (int n_ = 0; n_ < 2; ++n_) {                    \
            acc[(MB)+m_][(NB)+n_] = __builtin_amdgcn_mfma_f32_16x16x32_bf16(  \
                AF[m_][0], BF[n_][0], acc[(MB)+m_][(NB)+n_], 0, 0, 0);        \
            acc[(MB)+m_][(NB)+n_] = __builtin_amdgcn_mfma_f32_16x16x32_bf16(  \
                AF[m_][1], BF[n_][1], acc[(MB)+m_][(NB)+n_], 0, 0, 0);        \
        }                                                                     \
        __builtin_amdgcn_s_setprio(0);                                        \
        __builtin_amdgcn_s_barrier(); } while (0)

    const char* As0 = lds[0][0]; const char* Ws0 = lds[0][1];
    const char* As1 = lds[1][0]; const char* Ws1 = lds[1][1];

    // prologue: slot0 <- tile0 (all 4 halves), slot1.W <- tile1
    STAGE(0, 0, 0, 0, pA0, pA1);
    STAGE(0, 0, 1, 0, pA0, pA1);
    STAGE(0, 1, 0, 0, pW0, pW1);
    STAGE(0, 1, 1, 0, pW0, pW1);
    STAGE(1, 1, 0, 1, pW0, pW1);
    STAGE(1, 1, 1, 1, pW0, pW1);
    asm volatile("s_waitcnt vmcnt(4)" ::: "memory");
    __builtin_amdgcn_s_barrier();

    bf16x8 a0[4][2], a1[4][2], b0[2][2], b1[2][2];

    for (int it = 0; it < NT_ / 2; ++it) {
        const int t1 = 2 * it + 1;
        // P1: Q(m0-3,n0-1) of t0
        RDA(a0, As0, 0); RDB(b0, Ws0, 0);
        STAGE(1, 0, 0, t1, pA0, pA1);
        MIDBAR(); MFMAQ(a0, b0, 0, 0);
        // P2: Q(m0-3,n2-3)
        RDB(b1, Ws0, 2);
        STAGE(1, 0, 1, t1, pA0, pA1);
        MIDBAR(); MFMAQ(a0, b1, 0, 2);
        // P3: Q(m4-7,n0-1)
        RDA(a1, As0, 4);
        STAGE(0, 1, 0, t1 + 1, pW0, pW1);
        MIDBAR(); MFMAQ(a1, b0, 4, 0);
        // P4: Q(m4-7,n2-3); vmcnt(4) -> slot1 (P7,P8 prev + P1,P2) landed
        STAGE(0, 1, 1, t1 + 1, pW0, pW1);
        asm volatile("s_waitcnt vmcnt(4)" ::: "memory");
        MIDBAR(); MFMAQ(a1, b1, 4, 2);
        // P5: Q(m0-3,n0-1) of t1
        RDA(a0, As1, 0); RDB(b0, Ws1, 0);
        STAGE(0, 0, 0, t1 + 1, pA0, pA1);
        MIDBAR(); MFMAQ(a0, b0, 0, 0);
        // P6
        RDB(b1, Ws1, 2);
        STAGE(0, 0, 1, t1 + 1, pA0, pA1);
        MIDBAR(); MFMAQ(a0, b1, 0, 2);
        // P7
        RDA(a1, As1, 4);
        STAGE(1, 1, 0, t1 + 2, pW0, pW1);
        MIDBAR(); MFMAQ(a1, b0, 4, 0);
        // P8; vmcnt(4) -> slot0 (P3..P6) landed
        STAGE(1, 1, 1, t1 + 2, pW0, pW1);
        asm volatile("s_waitcnt vmcnt(4)" ::: "memory");
        MIDBAR(); MFMAQ(a1, b1, 4, 2);
    }

    // epilogue: C/D layout col=lane&15, row=(lane>>4)*4+j
    const int orow0 = bm * 256 + wr * 128;
    const int ocol0 = bn * 256 + wc * 64;
#pragma unroll
    for (int n = 0; n < 4; ++n) {
        int c = ocol0 + n * 16 + (lane & 15);
        float bv = bias[c];
#pragma unroll
        for (int m = 0; m < 8; ++m) {
            int r0 = orow0 + m * 16 + ((lane >> 4) << 2);
#pragma unroll
            for (int j = 0; j < 4; ++j)
                out[(size_t)(r0 + j) * OUT_ + c] = acc[m][n][j] + bv;
        }
    }
#undef DSR
#undef STAGE
#undef RDA
#undef RDB
#undef MIDBAR
#undef MFMAQ
}

// ---------------------------------------------------------------------------
// Fallback (no workspace): correct f32 path
// ---------------------------------------------------------------------------
__global__ __launch_bounds__(256) void kan_fallback(const float* __restrict__ x,
                                                    const float* __restrict__ bw,
                                                    const float* __restrict__ bb,
                                                    const float* __restrict__ sw,
                                                    const float* __restrict__ grid,
                                                    float* __restrict__ out) {
    __shared__ float ash[16 * 384];
    const int tid = threadIdx.x;
    const int o   = blockIdx.x * 256 + tid;
    const int b0  = blockIdx.y * 16;
    float acc[16];
#pragma unroll
    for (int r = 0; r < 16; ++r) acc[r] = 0.0f;

    for (int ic = 0; ic < IN_; ic += 64) {
        __syncthreads();
        for (int p = tid; p < 1024; p += 256) {
            int r = p >> 6, ii = p & 63;
            int i = ic + ii;
            float xv = x[(size_t)(b0 + r) * IN_ + i];
            float g[5];
#pragma unroll
            for (int j = 0; j < 5; ++j) g[j] = grid[i * 5 + j];
            float diff[5], bas[5];
#pragma unroll
            for (int j = 0; j < 5; ++j) {
                diff[j] = xv - g[j];
                bas[j]  = (diff[j] >= 0.0f && diff[j] < 1.0f) ? 1.0f : 0.0f;
            }
#pragma unroll
            for (int oo = 1; oo <= 3; ++oo) {
                float nb[4];
#pragma unroll
                for (int j = 0; j < 5 - oo; ++j) {
                    int i2 = min(j + oo, 4);
                    int i3 = min(j + oo + 1, 4);
                    nb[j] = (diff[j] - g[j]) / (g[i2] - g[j] + EPS) * bas[j]
                          + (g[i3] - diff[j]) / (g[i3] - g[j + 1] + EPS) * bas[j + 1];
                }
#pragma unroll
                for (int j = 0; j < 5 - oo; ++j) bas[j] = nb[j];
            }
            float* ap = &ash[r * 384 + ii * 6];
            ap[0] = xv;
#pragma unroll
            for (int j = 0; j < 5; ++j) ap[1 + j] = bas[j];
        }
        __syncthreads();
        for (int ii = 0; ii < 64; ++ii) {
            int i = ic + ii;
            float w0 = bw[(size_t)o * IN_ + i];
            const float* swp = sw + ((size_t)o * IN_ + i) * 5;
            float w1 = swp[0], w2 = swp[1], w3 = swp[2], w4 = swp[3], w5 = swp[4];
#pragma unroll
            for (int r = 0; r < 16; ++r) {
                const float* a = &ash[r * 384 + ii * 6];
                acc[r] += a[0] * w0 + a[1] * w1 + a[2] * w2
                        + a[3] * w3 + a[4] * w4 + a[5] * w5;
            }
        }
    }
    float bv = bb[o];
#pragma unroll
    for (int r = 0; r < 16; ++r)
        out[(size_t)(b0 + r) * OUT_ + o] = acc[r] + bv;
}

extern "C" void kernel_launch(void* const* d_in, const int* in_sizes, int n_in,
                              void* d_out, int out_size, void* d_ws, size_t ws_size,
                              hipStream_t stream) {
    (void)in_sizes; (void)n_in; (void)out_size;
    const float* x    = (const float*)d_in[0];
    const float* bw   = (const float*)d_in[1];
    const float* bb   = (const float*)d_in[2];
    const float* sw   = (const float*)d_in[3];
    const float* grid = (const float*)d_in[4];
    float* out = (float*)d_out;

    const size_t needA = (size_t)B_ * KA_ * sizeof(ushort);
    const size_t needW = (size_t)OUT_ * KA_ * sizeof(ushort);

    if (ws_size >= needA + needW) {
        ushort* A = (ushort*)d_ws;
        ushort* W = A + (size_t)B_ * KA_;
        stage_a<<<dim3(B_ / 16, IN_ / 256), 256, 0, stream>>>(x, grid, A);
        stage_w<<<dim3(OUT_, IN_ / 256), 256, 0, stream>>>(bw, sw, W);
        gemm_kan8<<<dim3(256), 512, 0, stream>>>(A, W, bb, out);
    } else {
        kan_fallback<<<dim3(OUT_ / 256, B_ / 16), 256, 0, stream>>>(x, bw, bb, sw, grid, out);
    }
}

// Round 4
// 422.433 us; speedup vs baseline: 1.4675x; 1.0568x over previous
//
#include <hip/hip_runtime.h>
#include <hip/hip_bf16.h>

#define EPS 1e-8f

constexpr int B_   = 8192;
constexpr int IN_  = 2048;
constexpr int OUT_ = 2048;
constexpr int KA_  = IN_ * 6;   // augmented K: [x, basis0..4] per input feature
constexpr int NT_  = KA_ / 64;  // 192 K-tiles of BK=64

typedef __bf16 bf16x8 __attribute__((ext_vector_type(8)));
typedef float  f32x4  __attribute__((ext_vector_type(4)));

__device__ __forceinline__ ushort f2bf(float f) {
    union { float f; uint u; } v; v.f = f;
    uint u = v.u;
    uint r = u + 0x7fffu + ((u >> 16) & 1u);   // RNE
    return (ushort)(r >> 16);
}

__device__ __forceinline__ void gload16(const void* g, void* l) {
    __builtin_amdgcn_global_load_lds(
        (const __attribute__((address_space(1))) void*)g,
        (__attribute__((address_space(3))) void*)l,
        16, 0, 0);
}

// ---------------------------------------------------------------------------
// Stage A: A_aug[b, i*6+c] bf16.  (unchanged, passed R2/R3)
// ---------------------------------------------------------------------------
__global__ __launch_bounds__(256) void stage_a(const float* __restrict__ x,
                                               const float* __restrict__ grid,
                                               ushort* __restrict__ A) {
    __shared__ __attribute__((aligned(16))) ushort pack[1536];
    const int tid = threadIdx.x;
    const int b0  = blockIdx.x * 16;
    const int i0  = blockIdx.y * 256;
    const int i   = i0 + tid;

    float g[5];
#pragma unroll
    for (int j = 0; j < 5; ++j) g[j] = grid[i * 5 + j];

    float r1[9], r2[9];
    {
        int t = 0;
#pragma unroll
        for (int o = 1; o <= 3; ++o) {
#pragma unroll
            for (int j = 0; j < 5 - o; ++j) {
                int i2 = min(j + o, 4);
                int i3 = min(j + o + 1, 4);
                r1[t] = 1.0f / (g[i2] - g[j] + EPS);
                r2[t] = 1.0f / (g[i3] - g[j + 1] + EPS);
                ++t;
            }
        }
    }

    for (int r = 0; r < 16; ++r) {
        const int b = b0 + r;
        float xv = x[(size_t)b * IN_ + i];
        float diff[5], bas[5];
#pragma unroll
        for (int j = 0; j < 5; ++j) {
            diff[j] = xv - g[j];
            bas[j]  = (diff[j] >= 0.0f && diff[j] < 1.0f) ? 1.0f : 0.0f;
        }
        int t = 0;
#pragma unroll
        for (int o = 1; o <= 3; ++o) {
            float nb[4];
#pragma unroll
            for (int j = 0; j < 5 - o; ++j) {
                int i3 = min(j + o + 1, 4);
                float t1 = (diff[j] - g[j]) * r1[t] * bas[j];
                float t2 = (g[i3] - diff[j]) * r2[t] * bas[j + 1];
                nb[j] = t1 + t2;
                ++t;
            }
#pragma unroll
            for (int j = 0; j < 5 - o; ++j) bas[j] = nb[j];
        }

        pack[tid * 6 + 0] = f2bf(xv);
#pragma unroll
        for (int j = 0; j < 5; ++j) pack[tid * 6 + 1 + j] = f2bf(bas[j]);
        __syncthreads();
        {
            const uint* ps = (const uint*)pack;
            uint* pd = (uint*)(A + (size_t)b * KA_ + (size_t)i0 * 6);
#pragma unroll
            for (int j = 0; j < 3; ++j) pd[tid + j * 256] = ps[tid + j * 256];
        }
        __syncthreads();
    }
}

// ---------------------------------------------------------------------------
// Stage W: W_aug[o, i*6+c] bf16.  (unchanged, passed R2/R3)
// ---------------------------------------------------------------------------
__global__ __launch_bounds__(256) void stage_w(const float* __restrict__ bw,
                                               const float* __restrict__ sw,
                                               ushort* __restrict__ W) {
    __shared__ __attribute__((aligned(16))) float  ssh[1280];
    __shared__ __attribute__((aligned(16))) ushort wsh[1536];
    const int tid = threadIdx.x;
    const int o   = blockIdx.x;
    const int i0  = blockIdx.y * 256;

    const float* sp = sw + ((size_t)o * IN_ + i0) * 5;
    for (int j = tid; j < 1280; j += 256) ssh[j] = sp[j];
    float bwv = bw[(size_t)o * IN_ + i0 + tid];
    __syncthreads();

    wsh[tid * 6] = f2bf(bwv);
#pragma unroll
    for (int j = 0; j < 5; ++j) wsh[tid * 6 + 1 + j] = f2bf(ssh[tid * 5 + j]);
    __syncthreads();

    const uint* ps = (const uint*)wsh;
    uint* pd = (uint*)(W + (size_t)o * KA_ + (size_t)i0 * 6);
#pragma unroll
    for (int j = 0; j < 3; ++j) pd[tid + j * 256] = ps[tid + j * 256];
}

// ---------------------------------------------------------------------------
// GEMM, 256x256 8-phase template (T1+T2+T3+T4+T5):
//   BM=BN=256, BK=64, 512 thr (8 waves, 2Mx4N), per-wave 128x64 out.
//   LDS 128 KiB: 2 slots x (A[256][64] + W[256][64]) bf16.
//   T2 swizzle (R4 fix): 3-bit XOR, phys 16B-slot = slot ^ (row&7)
//   (byte ^= (row&7)<<4).  Both-sides involution (rule #21):
//   linear gload_lds dest + source col (l&7)^((l>>3)&7) + XOR'd ds_read.
//   16-lane read group (16 rows, same slot) -> 8 slots x 2 lanes = free.
//   8 phases / 2 K-tiles per iter; counted vmcnt(4) at phases 4 & 8 only.
// grid: 256 blocks (1/CU), XCD-swizzled (256%8==0 -> bijective)
// ---------------------------------------------------------------------------
__global__ __launch_bounds__(512, 2) void gemm_kan8(const ushort* __restrict__ A,
                                                    const ushort* __restrict__ W,
                                                    const float* __restrict__ bias,
                                                    float* __restrict__ out) {
    __shared__ __attribute__((aligned(16))) char lds[2][2][32768];

    const int tid  = threadIdx.x;
    const int lane = tid & 63;
    const int wave = tid >> 6;
    const int wr   = wave >> 2;   // 0..1
    const int wc   = wave & 3;    // 0..3

    uint bid = blockIdx.x;
    uint swz = (bid & 7u) * 32u + (bid >> 3);   // XCD-contiguous chunks
    const int bm = (int)(swz >> 3);             // 0..31
    const int bn = (int)(swz & 7u);             // 0..7

    const uint lhi16 = ((uint)lane >> 4) * 16u;
    const uint swx   = ((uint)lane & 7u) << 4;  // (row&7)<<4 since row&7==lane&7
    uint aro[8], wro[4];
#pragma unroll
    for (int m = 0; m < 8; ++m) aro[m] = (uint)(wr * 128 + m * 16 + (lane & 15)) * 128u;
#pragma unroll
    for (int n = 0; n < 4; ++n) wro[n] = (uint)(wc * 64 + n * 16 + (lane & 15)) * 128u;

    // staging: chunk c=wave (rows 0-63 of half) / +8192B (rows 64-127);
    // lane -> LDS row c*8+(l>>3), phys slot l&7; global source col
    // (l&7)^(row&7) = (l&7)^((l>>3)&7)  [same 128B segment, lane-permuted]
    const uint srow0 = (uint)wave * 8u + ((uint)lane >> 3);
    const uint srow1 = srow0 + 64u;
    const uint gcol  = (((uint)lane & 7u) ^ (((uint)lane >> 3) & 7u)) * 8u;
    const ushort* pA0 = A + (size_t)bm * 256 * KA_ + (size_t)srow0 * KA_ + gcol;
    const ushort* pA1 = A + (size_t)bm * 256 * KA_ + (size_t)srow1 * KA_ + gcol;
    const ushort* pW0 = W + (size_t)bn * 256 * KA_ + (size_t)srow0 * KA_ + gcol;
    const ushort* pW1 = W + (size_t)bn * 256 * KA_ + (size_t)srow1 * KA_ + gcol;
    const uint c0off = (uint)wave * 1024u;
    const uint c1off = c0off + 8192u;

    f32x4 acc[8][4];
#pragma unroll
    for (int m = 0; m < 8; ++m)
#pragma unroll
        for (int n = 0; n < 4; ++n)
            acc[m][n] = (f32x4){0.f, 0.f, 0.f, 0.f};

#define DSR(base, ro, kh) (*(const bf16x8*)((base) + (ro) + (((kh) * 64u + lhi16) ^ swx)))

#define STAGE(s, mat, h, kk, PT0, PT1) do {                                   \
        uint kc_ = (uint)((kk) < NT_ ? (kk) : 0);                             \
        size_t go_ = (size_t)(h) * 128 * KA_ + (size_t)kc_ * 64;              \
        gload16(PT0 + go_, &lds[s][mat][(h) * 16384 + c0off]);                \
        gload16(PT1 + go_, &lds[s][mat][(h) * 16384 + c1off]);                \
    } while (0)

#define RDA(dst, base, mb) do {                                               \
        _Pragma("unroll") for (int m_ = 0; m_ < 4; ++m_) {                    \
            dst[m_][0] = DSR(base, aro[(mb) + m_], 0);                        \
            dst[m_][1] = DSR(base, aro[(mb) + m_], 1); } } while (0)

#define RDB(dst, base, nb) do {                                               \
        _Pragma("unroll") for (int n_ = 0; n_ < 2; ++n_) {                    \
            dst[n_][0] = DSR(base, wro[(nb) + n_], 0);                        \
            dst[n_][1] = DSR(base, wro[(nb) + n_], 1); } } while (0)

#define MIDBAR() do { __builtin_amdgcn_s_barrier();                           \
        asm volatile("s_waitcnt lgkmcnt(0)" ::: "memory");                    \
        __builtin_amdgcn_sched_barrier(0); } while (0)

#define MFMAQ(AF, BF, MB, NB) do {                                            \
        __builtin_amdgcn_s_setprio(1);                                        \
        _Pragma("unroll") for (int m_ = 0; m_ < 4; ++m_)                      \
        _Pragma("unroll") for (int n_ = 0; n_ < 2; ++n_) {                    \
            acc[(MB)+m_][(NB)+n_] = __builtin_amdgcn_mfma_f32_16x16x32_bf16(  \
                AF[m_][0], BF[n_][0], acc[(MB)+m_][(NB)+n_], 0, 0, 0);        \
            acc[(MB)+m_][(NB)+n_] = __builtin_amdgcn_mfma_f32_16x16x32_bf16(  \
                AF[m_][1], BF[n_][1], acc[(MB)+m_][(NB)+n_], 0, 0, 0);        \
        }                                                                     \
        __builtin_amdgcn_s_setprio(0);                                        \
        __builtin_amdgcn_s_barrier(); } while (0)

    const char* As0 = lds[0][0]; const char* Ws0 = lds[0][1];
    const char* As1 = lds[1][0]; const char* Ws1 = lds[1][1];

    // prologue: slot0 <- tile0 (all 4 halves), slot1.W <- tile1
    STAGE(0, 0, 0, 0, pA0, pA1);
    STAGE(0, 0, 1, 0, pA0, pA1);
    STAGE(0, 1, 0, 0, pW0, pW1);
    STAGE(0, 1, 1, 0, pW0, pW1);
    STAGE(1, 1, 0, 1, pW0, pW1);
    STAGE(1, 1, 1, 1, pW0, pW1);
    asm volatile("s_waitcnt vmcnt(4)" ::: "memory");
    __builtin_amdgcn_s_barrier();

    bf16x8 a0[4][2], a1[4][2], b0[2][2], b1[2][2];

    for (int it = 0; it < NT_ / 2; ++it) {
        const int t1 = 2 * it + 1;
        // P1: Q(m0-3,n0-1) of t0
        RDA(a0, As0, 0); RDB(b0, Ws0, 0);
        STAGE(1, 0, 0, t1, pA0, pA1);
        MIDBAR(); MFMAQ(a0, b0, 0, 0);
        // P2: Q(m0-3,n2-3)
        RDB(b1, Ws0, 2);
        STAGE(1, 0, 1, t1, pA0, pA1);
        MIDBAR(); MFMAQ(a0, b1, 0, 2);
        // P3: Q(m4-7,n0-1)
        RDA(a1, As0, 4);
        STAGE(0, 1, 0, t1 + 1, pW0, pW1);
        MIDBAR(); MFMAQ(a1, b0, 4, 0);
        // P4: Q(m4-7,n2-3); vmcnt(4) -> slot1 (P7,P8 prev + P1,P2) landed
        STAGE(0, 1, 1, t1 + 1, pW0, pW1);
        asm volatile("s_waitcnt vmcnt(4)" ::: "memory");
        MIDBAR(); MFMAQ(a1, b1, 4, 2);
        // P5: Q(m0-3,n0-1) of t1
        RDA(a0, As1, 0); RDB(b0, Ws1, 0);
        STAGE(0, 0, 0, t1 + 1, pA0, pA1);
        MIDBAR(); MFMAQ(a0, b0, 0, 0);
        // P6
        RDB(b1, Ws1, 2);
        STAGE(0, 0, 1, t1 + 1, pA0, pA1);
        MIDBAR(); MFMAQ(a0, b1, 0, 2);
        // P7
        RDA(a1, As1, 4);
        STAGE(1, 1, 0, t1 + 2, pW0, pW1);
        MIDBAR(); MFMAQ(a1, b0, 4, 0);
        // P8; vmcnt(4) -> slot0 (P3..P6) landed
        STAGE(1, 1, 1, t1 + 2, pW0, pW1);
        asm volatile("s_waitcnt vmcnt(4)" ::: "memory");
        MIDBAR(); MFMAQ(a1, b1, 4, 2);
    }

    // epilogue: C/D layout col=lane&15, row=(lane>>4)*4+j
    const int orow0 = bm * 256 + wr * 128;
    const int ocol0 = bn * 256 + wc * 64;
#pragma unroll
    for (int n = 0; n < 4; ++n) {
        int c = ocol0 + n * 16 + (lane & 15);
        float bv = bias[c];
#pragma unroll
        for (int m = 0; m < 8; ++m) {
            int r0 = orow0 + m * 16 + ((lane >> 4) << 2);
#pragma unroll
            for (int j = 0; j < 4; ++j)
                out[(size_t)(r0 + j) * OUT_ + c] = acc[m][n][j] + bv;
        }
    }
#undef DSR
#undef STAGE
#undef RDA
#undef RDB
#undef MIDBAR
#undef MFMAQ
}

// ---------------------------------------------------------------------------
// Fallback (no workspace): correct f32 path
// ---------------------------------------------------------------------------
__global__ __launch_bounds__(256) void kan_fallback(const float* __restrict__ x,
                                                    const float* __restrict__ bw,
                                                    const float* __restrict__ bb,
                                                    const float* __restrict__ sw,
                                                    const float* __restrict__ grid,
                                                    float* __restrict__ out) {
    __shared__ float ash[16 * 384];
    const int tid = threadIdx.x;
    const int o   = blockIdx.x * 256 + tid;
    const int b0  = blockIdx.y * 16;
    float acc[16];
#pragma unroll
    for (int r = 0; r < 16; ++r) acc[r] = 0.0f;

    for (int ic = 0; ic < IN_; ic += 64) {
        __syncthreads();
        for (int p = tid; p < 1024; p += 256) {
            int r = p >> 6, ii = p & 63;
            int i = ic + ii;
            float xv = x[(size_t)(b0 + r) * IN_ + i];
            float g[5];
#pragma unroll
            for (int j = 0; j < 5; ++j) g[j] = grid[i * 5 + j];
            float diff[5], bas[5];
#pragma unroll
            for (int j = 0; j < 5; ++j) {
                diff[j] = xv - g[j];
                bas[j]  = (diff[j] >= 0.0f && diff[j] < 1.0f) ? 1.0f : 0.0f;
            }
#pragma unroll
            for (int oo = 1; oo <= 3; ++oo) {
                float nb[4];
#pragma unroll
                for (int j = 0; j < 5 - oo; ++j) {
                    int i2 = min(j + oo, 4);
                    int i3 = min(j + oo + 1, 4);
                    nb[j] = (diff[j] - g[j]) / (g[i2] - g[j] + EPS) * bas[j]
                          + (g[i3] - diff[j]) / (g[i3] - g[j + 1] + EPS) * bas[j + 1];
                }
#pragma unroll
                for (int j = 0; j < 5 - oo; ++j) bas[j] = nb[j];
            }
            float* ap = &ash[r * 384 + ii * 6];
            ap[0] = xv;
#pragma unroll
            for (int j = 0; j < 5; ++j) ap[1 + j] = bas[j];
        }
        __syncthreads();
        for (int ii = 0; ii < 64; ++ii) {
            int i = ic + ii;
            float w0 = bw[(size_t)o * IN_ + i];
            const float* swp = sw + ((size_t)o * IN_ + i) * 5;
            float w1 = swp[0], w2 = swp[1], w3 = swp[2], w4 = swp[3], w5 = swp[4];
#pragma unroll
            for (int r = 0; r < 16; ++r) {
                const float* a = &ash[r * 384 + ii * 6];
                acc[r] += a[0] * w0 + a[1] * w1 + a[2] * w2
                        + a[3] * w3 + a[4] * w4 + a[5] * w5;
            }
        }
    }
    float bv = bb[o];
#pragma unroll
    for (int r = 0; r < 16; ++r)
        out[(size_t)(b0 + r) * OUT_ + o] = acc[r] + bv;
}

extern "C" void kernel_launch(void* const* d_in, const int* in_sizes, int n_in,
                              void* d_out, int out_size, void* d_ws, size_t ws_size,
                              hipStream_t stream) {
    (void)in_sizes; (void)n_in; (void)out_size;
    const float* x    = (const float*)d_in[0];
    const float* bw   = (const float*)d_in[1];
    const float* bb   = (const float*)d_in[2];
    const float* sw   = (const float*)d_in[3];
    const float* grid = (const float*)d_in[4];
    float* out = (float*)d_out;

    const size_t needA = (size_t)B_ * KA_ * sizeof(ushort);
    const size_t needW = (size_t)OUT_ * KA_ * sizeof(ushort);

    if (ws_size >= needA + needW) {
        ushort* A = (ushort*)d_ws;
        ushort* W = A + (size_t)B_ * KA_;
        stage_a<<<dim3(B_ / 16, IN_ / 256), 256, 0, stream>>>(x, grid, A);
        stage_w<<<dim3(OUT_, IN_ / 256), 256, 0, stream>>>(bw, sw, W);
        gemm_kan8<<<dim3(256), 512, 0, stream>>>(A, W, bb, out);
    } else {
        kan_fallback<<<dim3(OUT_ / 256, B_ / 16), 256, 0, stream>>>(x, bw, bb, sw, grid, out);
    }
}